// Round 2
// baseline (5265.582 us; speedup 1.0000x reference)
//
#include <hip/hip_runtime.h>
#include <math.h>

#define B 64
#define H 1024
#define V 16384
#define T 64
constexpr size_t TBV = (size_t)T * B * V;

typedef __attribute__((ext_vector_type(8))) short bhalf8;
typedef __attribute__((ext_vector_type(16))) float f32x16;

// Truncation split: a = hi + lo with hi = top-16-bits(a). |lo| <= 2^-8 |a|,
// lo stored as truncated bf16 -> total representation error ~2^-16 relative.
__device__ __forceinline__ void split_trunc(float a, unsigned short& hi, unsigned short& lo) {
    unsigned u = __float_as_uint(a);
    hi = (unsigned short)(u >> 16);
    float hif = __uint_as_float(u & 0xFFFF0000u);
    lo = (unsigned short)(__float_as_uint(a - hif) >> 16);
}

__device__ __forceinline__ void cvt8(const float* f, int4& hv, int4& lv) {
    unsigned h[8], l[8];
#pragma unroll
    for (int j = 0; j < 8; ++j) {
        unsigned u = __float_as_uint(f[j]);
        h[j] = u >> 16;
        float hif = __uint_as_float(u & 0xFFFF0000u);
        l[j] = __float_as_uint(f[j] - hif) >> 16;
    }
    hv = make_int4((int)(h[0] | (h[1] << 16)), (int)(h[2] | (h[3] << 16)),
                   (int)(h[4] | (h[5] << 16)), (int)(h[6] | (h[7] << 16)));
    lv = make_int4((int)(l[0] | (l[1] << 16)), (int)(l[2] | (l[3] << 16)),
                   (int)(l[4] | (l[5] << 16)), (int)(l[6] | (l[7] << 16)));
}

// ---------------- shared GEMM body ----------------
// C[b, n0+nn] (+)= sum_k A[b, k0+k] * W[n0+nn, k0+k], b in [0,64), nn in [0,128),
// k over nChunks*64. A given as bf16 hi/lo fragment planes: plane[kg*512 + row*8 + e],
// kg = k>>3. W fp32 row-major [n][1024], converted to hi/lo bf16 in LDS staging.
// 3-product split MFMA (32x32x16). dst[b*dstride + n] = acc (overwrite).
__device__ __forceinline__ void gemm_body(
    const unsigned short* __restrict__ Ahi, const unsigned short* __restrict__ Alo,
    const float* __restrict__ W, int k0, int nChunks,
    float* __restrict__ dst, size_t dstride, int n0,
    short (&sBh)[2][128][72], short (&sBl)[2][128][72])
{
    const int tid  = threadIdx.x;
    const int wave = tid >> 6;
    const int lane = tid & 63;
    const int lrow = lane & 31;
    const int lhalf = lane >> 5;

    f32x16 acc0, acc1;
#pragma unroll
    for (int i = 0; i < 16; ++i) { acc0[i] = 0.f; acc1[i] = 0.f; }

    const int r  = tid >> 1;          // staging row 0..127
    const int kh = (tid & 1) * 32;    // staging k-half

    // stage chunk 0
    {
        const float* wr = W + (size_t)(n0 + r) * H + k0 + kh;
        float f[32];
#pragma unroll
        for (int i = 0; i < 32; i += 4) *(float4*)&f[i] = *(const float4*)&wr[i];
#pragma unroll
        for (int i = 0; i < 32; i += 8) {
            int4 hv, lv; cvt8(&f[i], hv, lv);
            *(int4*)&sBh[0][r][kh + i] = hv;
            *(int4*)&sBl[0][r][kh + i] = lv;
        }
    }
    __syncthreads();

    for (int c = 0; c < nChunks; ++c) {
        const int buf = c & 1;
        float pf[32];
        const bool pre = (c + 1 < nChunks);
        if (pre) {  // issue next chunk's global loads early (hide under MFMA)
            const float* wr = W + (size_t)(n0 + r) * H + k0 + (c + 1) * 64 + kh;
#pragma unroll
            for (int i = 0; i < 32; i += 4) *(float4*)&pf[i] = *(const float4*)&wr[i];
        }
        const int kgb = ((k0 + c * 64) >> 3) + lhalf;
#pragma unroll
        for (int kt = 0; kt < 4; ++kt) {
            const bhalf8 bh = *(const bhalf8*)&sBh[buf][wave * 32 + lrow][kt * 16 + lhalf * 8];
            const bhalf8 bl = *(const bhalf8*)&sBl[buf][wave * 32 + lrow][kt * 16 + lhalf * 8];
            const size_t aoff = (size_t)(kgb + kt * 2) * 512 + (size_t)lrow * 8;
            const bhalf8 ah0 = *(const bhalf8*)(Ahi + aoff);
            const bhalf8 al0 = *(const bhalf8*)(Alo + aoff);
            const bhalf8 ah1 = *(const bhalf8*)(Ahi + aoff + 256);
            const bhalf8 al1 = *(const bhalf8*)(Alo + aoff + 256);
            acc0 = __builtin_amdgcn_mfma_f32_32x32x16_bf16(ah0, bh, acc0, 0, 0, 0);
            acc0 = __builtin_amdgcn_mfma_f32_32x32x16_bf16(ah0, bl, acc0, 0, 0, 0);
            acc0 = __builtin_amdgcn_mfma_f32_32x32x16_bf16(al0, bh, acc0, 0, 0, 0);
            acc1 = __builtin_amdgcn_mfma_f32_32x32x16_bf16(ah1, bh, acc1, 0, 0, 0);
            acc1 = __builtin_amdgcn_mfma_f32_32x32x16_bf16(ah1, bl, acc1, 0, 0, 0);
            acc1 = __builtin_amdgcn_mfma_f32_32x32x16_bf16(al1, bh, acc1, 0, 0, 0);
        }
        if (pre) {
#pragma unroll
            for (int i = 0; i < 32; i += 8) {
                int4 hv, lv; cvt8(&pf[i], hv, lv);
                *(int4*)&sBh[buf ^ 1][r][kh + i] = hv;
                *(int4*)&sBl[buf ^ 1][r][kh + i] = lv;
            }
        }
        __syncthreads();
    }

    // epilogue: C/D layout col=lane&31, row=(reg&3)+8*(reg>>2)+4*(lane>>5)
    const int n = n0 + wave * 32 + lrow;
#pragma unroll
    for (int reg = 0; reg < 16; ++reg) {
        int row = (reg & 3) + 8 * (reg >> 2) + 4 * lhalf;
        dst[(size_t)row * dstride + n]        = acc0[reg];
        dst[(size_t)(row + 32) * dstride + n] = acc1[reg];
    }
}

// ---------------- gates GEMM: grid 64 = 32 ntiles x 2 (x/W_ih | h/W_hh) ----------------
__global__ __launch_bounds__(256, 2) void k_gates(
    const unsigned short* __restrict__ xh, const unsigned short* __restrict__ xl,
    const unsigned short* __restrict__ hh, const unsigned short* __restrict__ hl,
    const float* __restrict__ W_ih, const float* __restrict__ W_hh,
    float* __restrict__ gpart)
{
    __shared__ short sBh[2][128][72];
    __shared__ short sBl[2][128][72];
    const int nt = blockIdx.x >> 1, ks = blockIdx.x & 1;
    if (ks == 0)
        gemm_body(xh, xl, W_ih, 0, 16, gpart, 4096, nt * 128, sBh, sBl);
    else
        gemm_body(hh, hl, W_hh, 0, 16, gpart + (size_t)B * 4096, 4096, nt * 128, sBh, sBl);
}

// ---------------- reduce gate partials + LSTM pointwise -> c, h-frags ----------------
__global__ __launch_bounds__(256) void k_lstm(
    const float* __restrict__ gpart,
    const float* __restrict__ b_ih, const float* __restrict__ b_hh,
    float* __restrict__ c,
    unsigned short* __restrict__ hh, unsigned short* __restrict__ hl)
{
    int idx = blockIdx.x * 256 + threadIdx.x;   // b*1024 + j
    int b = idx >> 10, j = idx & 1023;
    float s[4];
#pragma unroll
    for (int g = 0; g < 4; ++g) {
        int m = g * 1024 + j;
        s[g] = b_ih[m] + b_hh[m] + gpart[(size_t)b * 4096 + m]
             + gpart[(size_t)(B + b) * 4096 + m];
    }
    float ig = 1.f / (1.f + expf(-s[0]));
    float fg = 1.f / (1.f + expf(-s[1]));
    float gg = tanhf(s[2]);
    float og = 1.f / (1.f + expf(-s[3]));
    float cn = fg * c[idx] + ig * gg;
    float hn = og * tanhf(cn);
    c[idx] = cn;
    unsigned short hi, lo; split_trunc(hn, hi, lo);
    size_t fo = (size_t)(j >> 3) * 512 + (size_t)b * 8 + (j & 7);
    hh[fo] = hi; hl[fo] = lo;
}

// ---------------- logits GEMM: grid 256 = 128 ntiles x 2 ksplit ----------------
__global__ __launch_bounds__(256, 2) void k_logits(
    const unsigned short* __restrict__ hh, const unsigned short* __restrict__ hl,
    const float* __restrict__ W_out, float* __restrict__ out0, float* __restrict__ lpart)
{
    __shared__ short sBh[2][128][72];
    __shared__ short sBl[2][128][72];
    const int nt = blockIdx.x >> 1, ks = blockIdx.x & 1;
    gemm_body(hh, hl, W_out, ks * 512, 8, ks ? lpart : out0, V, nt * 128, sBh, sBl);
}

// ---------------- finalize logits (+bias), argmax, one-hot, mask, x-frags ----------------
__global__ __launch_bounds__(256) void k_argmax(
    float* __restrict__ logit_t, const float* __restrict__ lpart,
    const float* __restrict__ b_out, const float* __restrict__ embedding,
    const int* __restrict__ eos_ptr, float* __restrict__ mask,
    unsigned short* __restrict__ xh, unsigned short* __restrict__ xl,
    float* __restrict__ predicts_t, float* __restrict__ masks_t)
{
    const int b = blockIdx.x, tid = threadIdx.x;
    __shared__ float sval[256];
    __shared__ int   sidx[256];

    float best = -INFINITY;
    int bi = 0;
    for (int v = tid; v < V; v += 256) {
        size_t off = (size_t)b * V + v;
        float val = logit_t[off] + lpart[off] + b_out[v];
        logit_t[off] = val;
        if (val > best) { best = val; bi = v; }   // ascending scan -> earliest max kept
    }
    sval[tid] = best; sidx[tid] = bi;
    __syncthreads();
    for (int s = 128; s > 0; s >>= 1) {
        if (tid < s) {
            float v2 = sval[tid + s]; int i2 = sidx[tid + s];
            if (v2 > sval[tid] || (v2 == sval[tid] && i2 < sidx[tid])) {
                sval[tid] = v2; sidx[tid] = i2;
            }
        }
        __syncthreads();
    }
    int idx = sidx[0];
    if (tid == 0) {
        predicts_t[(size_t)b * V + idx] = 1.0f;
        float mb = mask[b];
        masks_t[b] = mb;                          // output OLD mask (pre-update)
        if (idx == *eos_ptr) mask[b] = 0.0f;
    }
    // x[b,:] = embedding[idx,:] -> bf16 hi/lo fragment planes
    for (int k = tid; k < H; k += 256) {
        unsigned short hi, lo; split_trunc(embedding[(size_t)idx * H + k], hi, lo);
        size_t fo = (size_t)(k >> 3) * 512 + (size_t)b * 8 + (k & 7);
        xh[fo] = hi; xl[fo] = lo;
    }
}

// ---------------- init ----------------
__global__ __launch_bounds__(256) void k_init(
    const float* __restrict__ enc_h, const float* __restrict__ enc_c,
    const float* __restrict__ init_input,
    float* __restrict__ c,
    unsigned short* __restrict__ hh, unsigned short* __restrict__ hl,
    unsigned short* __restrict__ xh, unsigned short* __restrict__ xl,
    float* __restrict__ mask)
{
    int i = blockIdx.x * 256 + threadIdx.x;      // covers B*H
    int b = i >> 10, j = i & 1023;
    c[i] = enc_c[i];
    unsigned short hi, lo;
    split_trunc(enc_h[i], hi, lo);
    size_t fo = (size_t)(j >> 3) * 512 + (size_t)b * 8 + (j & 7);
    hh[fo] = hi; hl[fo] = lo;
    split_trunc(init_input[j], hi, lo);
    xh[fo] = hi; xl[fo] = lo;
    if (i < B) mask[i] = 1.0f;
}

extern "C" void kernel_launch(void* const* d_in, const int* in_sizes, int n_in,
                              void* d_out, int out_size, void* d_ws, size_t ws_size,
                              hipStream_t stream)
{
    (void)in_sizes; (void)n_in; (void)out_size; (void)ws_size;

    const float* enc_h = (const float*)d_in[0];
    const float* enc_c = (const float*)d_in[1];
    const float* W_ih  = (const float*)d_in[2];
    const float* W_hh  = (const float*)d_in[3];
    const float* b_ih  = (const float*)d_in[4];
    const float* b_hh  = (const float*)d_in[5];
    const float* W_out = (const float*)d_in[6];
    const float* b_out = (const float*)d_in[7];
    const float* emb   = (const float*)d_in[8];
    const float* init_input = (const float*)d_in[9];
    const int* eos_ptr = (const int*)d_in[11];

    float* out = (float*)d_out;
    float* ws  = (float*)d_ws;
    // workspace carve (~7 MB)
    float* c     = ws;                         // 65536
    float* mask  = c + 65536;                  // 64
    float* gpart = mask + 64;                  // 2*64*4096 = 524288
    float* lpart = gpart + 524288;             // 64*16384 = 1048576
    unsigned short* xh = (unsigned short*)(lpart + 1048576);  // 65536 each
    unsigned short* xl = xh + 65536;
    unsigned short* hh = xl + 65536;
    unsigned short* hl = hh + 65536;

    hipMemsetAsync(d_out, 0, TBV * sizeof(float), stream);   // predicts region
    k_init<<<256, 256, 0, stream>>>(enc_h, enc_c, init_input, c, hh, hl, xh, xl, mask);

    for (int t = 0; t < T; ++t) {
        float* predicts_t = out + (size_t)t * B * V;
        float* logits_t   = out + TBV + (size_t)t * B * V;
        float* masks_t    = out + 2 * TBV + (size_t)t * B;

        k_gates<<<64, 256, 0, stream>>>(xh, xl, hh, hl, W_ih, W_hh, gpart);
        k_lstm<<<256, 256, 0, stream>>>(gpart, b_ih, b_hh, c, hh, hl);
        k_logits<<<256, 256, 0, stream>>>(hh, hl, W_out, logits_t, lpart);
        k_argmax<<<64, 256, 0, stream>>>(logits_t, lpart, b_out, emb, eos_ptr,
                                         mask, xh, xl, predicts_t, masks_t);
    }
}